// Round 10
// baseline (137.025 us; speedup 1.0000x reference)
//
#include <hip/hip_runtime.h>

// MoE dense: N=16384, D=256, E=8, H=128 (gate hidden), expert hidden 256.
// R17: producer/consumer wave specialization. Register-residency for x failed
// 3x (R12/R15/R16: compiler caps at 128 VGPR); R14b's 48us = near-serial sum
// of MFMA 16.6 + LDS 20.5 + VMEM 15 + VALU 12 us/CU. The LDS term is 8-wave
// multicast (every wave re-reads the full x and Hs panels). Split: waves 0-3
// = producers (GEMM1(e), 64 h each, weights L2->reg in-loop, write Hs[e&1]);
// waves 4-7 = consumers (GEMM2(e-1), 64 d each, accumulate across experts).
// 9-iter pipeline, 1 barrier/iter. LDS reads halve (->~10us); each SIMD has
// 1 producer + 1 consumer -> MFMA/VMEM/VALU overlap by construction. hacc and
// oacc share one acc[4][4] (disjoint wave paths) -> ~140 VGPR demand.
// Numerics bitwise-identical to R14b (same (kt,c)/(ht,c) order, f2bf, bias).
// Workspace:
//   w1f  fragment-major W1 @ 8388608   (1MB)
//   wg1f fragment-major Wg1 @ 9437184  (64KB)
//   w2f  fragment-major W2 @ 9502720   (1MB)

typedef unsigned short USH;
typedef float f32x4 __attribute__((ext_vector_type(4)));
typedef __bf16 bf16x8 __attribute__((ext_vector_type(8)));

__device__ __forceinline__ USH f2bf(float f) {
  unsigned int u = __float_as_uint(f);
  u += 0x7fffu + ((u >> 16) & 1u);   // RNE
  return (USH)(u >> 16);
}

// ---------------- prep (weights only) ----------------
// w1f fragment layout: value W1[e][c][h]; t=h>>4, kt=c>>6, ch=(c>>5)&1,
//   q=(c>>3)&3, u=c&7:  idx = ((e*64+kt*16+t)*2+ch)*512 + (q*16+(h&15))*8 + u
// w2f same with (h->k-role, d->out-role): value W2[e][h][d].
// wg1f: value Wg1[c][h], h in [0,128): idx = ((kt*8+t)*2+ch)*512 + ...

__global__ __launch_bounds__(256) void k_prep(
    const float* __restrict__ Wg1,
    const float* __restrict__ W1,
    const float* __restrict__ W2,
    USH* __restrict__ w1f, USH* __restrict__ w2f, USH* __restrict__ wg1f) {
  __shared__ float T[64][65];
  int b = blockIdx.x, tid = threadIdx.x;

  if (b < 128) {                // w1f
    int e = b >> 4, tl = b & 15;
    int c0 = (tl >> 2) * 64, h0 = (tl & 3) * 64;
    const float* src = W1 + (size_t)e * 65536;
#pragma unroll
    for (int p = 0; p < 4; ++p) {
      int r = p * 16 + (tid >> 4), d4 = (tid & 15) * 4;
      float4 v = *(const float4*)(src + (size_t)(c0 + r) * 256 + h0 + d4);
      T[r][d4] = v.x; T[r][d4 + 1] = v.y; T[r][d4 + 2] = v.z; T[r][d4 + 3] = v.w;
    }
    __syncthreads();
#pragma unroll
    for (int p = 0; p < 4; ++p) {
      int hr = p * 16 + (tid >> 4), c4 = (tid & 15) * 4;
      USH w[4];
#pragma unroll
      for (int j = 0; j < 4; ++j) w[j] = f2bf(T[c4 + j][hr]);   // W1[e][c0+c4+j][h0+hr]
      int h = h0 + hr;
      int t = h >> 4, lh = h & 15;
      int kt = c0 >> 6, ch = (c4 >> 5) & 1, q = (c4 >> 3) & 3, u0 = c4 & 7;
      size_t idx = ((size_t)((e * 64 + kt * 16 + t) * 2 + ch)) * 512 + (q * 16 + lh) * 8 + u0;
      *(uint2*)(w1f + idx) = *(const uint2*)w;
    }
  } else if (b < 256) {         // w2f
    int bp = b - 128;
    int e = bp >> 4, tl = bp & 15;
    int h0 = (tl >> 2) * 64, d0 = (tl & 3) * 64;
    const float* src = W2 + (size_t)e * 65536;
#pragma unroll
    for (int p = 0; p < 4; ++p) {
      int r = p * 16 + (tid >> 4), d4 = (tid & 15) * 4;
      float4 v = *(const float4*)(src + (size_t)(h0 + r) * 256 + d0 + d4);
      T[r][d4] = v.x; T[r][d4 + 1] = v.y; T[r][d4 + 2] = v.z; T[r][d4 + 3] = v.w;
    }
    __syncthreads();
#pragma unroll
    for (int p = 0; p < 4; ++p) {
      int dr = p * 16 + (tid >> 4), h4 = (tid & 15) * 4;
      USH w[4];
#pragma unroll
      for (int j = 0; j < 4; ++j) w[j] = f2bf(T[h4 + j][dr]);   // W2[e][h0+h4+j][d0+dr]
      int d = d0 + dr;
      int t = d >> 4, ld = d & 15;
      int ht = h0 >> 6, ch = (h4 >> 5) & 1, q = (h4 >> 3) & 3, u0 = h4 & 7;
      size_t idx = ((size_t)((e * 64 + ht * 16 + t) * 2 + ch)) * 512 + (q * 16 + ld) * 8 + u0;
      *(uint2*)(w2f + idx) = *(const uint2*)w;
    }
  } else {                      // wg1f (8 blocks)
    int bp = b - 256;
    int c0 = (bp >> 1) * 64, h0 = (bp & 1) * 64;
#pragma unroll
    for (int p = 0; p < 4; ++p) {
      int r = p * 16 + (tid >> 4), d4 = (tid & 15) * 4;
      float4 v = *(const float4*)(Wg1 + (size_t)(c0 + r) * 128 + h0 + d4);
      T[r][d4] = v.x; T[r][d4 + 1] = v.y; T[r][d4 + 2] = v.z; T[r][d4 + 3] = v.w;
    }
    __syncthreads();
#pragma unroll
    for (int p = 0; p < 4; ++p) {
      int hr = p * 16 + (tid >> 4), c4 = (tid & 15) * 4;
      USH w[4];
#pragma unroll
      for (int j = 0; j < 4; ++j) w[j] = f2bf(T[c4 + j][hr]);   // Wg1[c0+c4+j][h0+hr]
      int h = h0 + hr;
      int t = h >> 4, lh = h & 15;
      int kt = c0 >> 6, ch = (c4 >> 5) & 1, q = (c4 >> 3) & 3, u0 = c4 & 7;
      size_t idx = ((size_t)((kt * 8 + t) * 2 + ch)) * 512 + (q * 16 + lh) * 8 + u0;
      *(uint2*)(wg1f + idx) = *(const uint2*)w;
    }
  }
}

// ---------------- fused gate + experts (256 blocks x 64 rows, 512 thr) ------

__global__ __launch_bounds__(512, 2) void k_moe(
    const float* __restrict__ x,
    const USH* __restrict__ w1f,
    const USH* __restrict__ w2f,
    const USH* __restrict__ wg1f,
    const float* __restrict__ wg2,
    const float* __restrict__ bg1,
    const float* __restrict__ bg2,
    const float* __restrict__ b1,
    const float* __restrict__ b2,
    float* __restrict__ out) {
  __shared__ __align__(16) USH xs[4 * 64 * 64];   // 32KB, swizzled x tile
  __shared__ __align__(16) USH Hs[2][64 * 256];   // 64KB dbuf; Hs[0] doubles as hgs
  __shared__ float b1s[2048];
  __shared__ float b2s[2048];
  __shared__ float gse[512];                      // gse[e*64+n]
  __shared__ float wg2t[8 * 132];                 // wg2t[e][k], padded
  __shared__ float lgg[512];
  __shared__ float bg1s[128];
  __shared__ float bg2g[8];

  int tid = threadIdx.x;
  int wave = tid >> 6, lane = tid & 63;
  int quad = lane >> 4, l16 = lane & 15;
  int sw = l16 & 7;
  int rowBase = blockIdx.x * 64;
  float* hgs = (float*)&Hs[0][0];                 // 64x128 f32, slot-swizzled

  // ---- prologue: x f32 -> bf16 -> xs (swizzled); gate/bias constants
#pragma unroll
  for (int it = 0; it < 4; ++it) {
    int i = it * 512 + tid;
    int kt = i >> 9, rem = i & 511;
    int r = rem >> 3, slot = rem & 7;
    int c8 = slot ^ (r & 7);
    const float* sp = x + (size_t)(rowBase + r) * 256 + kt * 64 + c8 * 8;
    float4 a = *(const float4*)sp;
    float4 bq = *(const float4*)(sp + 4);
    USH v[8];
    v[0] = f2bf(a.x);  v[1] = f2bf(a.y);  v[2] = f2bf(a.z);  v[3] = f2bf(a.w);
    v[4] = f2bf(bq.x); v[5] = f2bf(bq.y); v[6] = f2bf(bq.z); v[7] = f2bf(bq.w);
    *(uint4*)(xs + (size_t)i * 8) = *(const uint4*)v;
  }
#pragma unroll
  for (int t = 0; t < 4; ++t) {
    b1s[t * 512 + tid] = b1[t * 512 + tid];
    b2s[t * 512 + tid] = b2[t * 512 + tid];
  }
  for (int t = tid; t < 1024; t += 512) wg2t[(t & 7) * 132 + (t >> 3)] = wg2[t];
  if (tid < 128) bg1s[tid] = bg1[tid];
  if (tid < 8) bg2g[tid] = bg2[tid];

  asm volatile("s_waitcnt lgkmcnt(0)" ::: "memory");
  __builtin_amdgcn_s_barrier();

  // ---- gate stage 1: hg^T[h,n] = sum_c Wg1[c,h]*x[n,c]; wave owns 16 h.
  {
    f32x4 hg4[4] = {};
#pragma unroll
    for (int kt = 0; kt < 4; ++kt)
#pragma unroll
      for (int c = 0; c < 2; ++c) {
        int cs = ((c * 4 + quad) ^ sw) * 8;
        bf16x8 av = *(const bf16x8*)(wg1f + (size_t)((kt * 8 + wave) * 2 + c) * 512 + lane * 8);
        bf16x8 bv[4];
#pragma unroll
        for (int j = 0; j < 4; ++j)
          bv[j] = *(const bf16x8*)(xs + kt * 4096 + (j * 16 + l16) * 64 + cs);
#pragma unroll
        for (int j = 0; j < 4; ++j)
          hg4[j] = __builtin_amdgcn_mfma_f32_16x16x32_bf16(av, bv[j], hg4[j], 0, 0, 0);
      }
    // hgs[n][h] = relu(hg + bg1), h-slot XOR-swizzled (slot = (h>>2)^(n&7))
    int hb = wave * 16 + quad * 4;
    int slotbase = wave * 4 + quad;
#pragma unroll
    for (int j = 0; j < 4; ++j) {
      int n = j * 16 + l16;
      int slot = slotbase ^ (n & 7);
      f32x4 v;
#pragma unroll
      for (int r = 0; r < 4; ++r) v[r] = fmaxf(hg4[j][r] + bg1s[hb + r], 0.0f);
      *(f32x4*)(hgs + n * 128 + slot * 4) = v;
    }
  }
  asm volatile("s_waitcnt lgkmcnt(0)" ::: "memory");
  __builtin_amdgcn_s_barrier();

  // ---- gate stage 2: logits[n][e] (f32, same k-order as before)
  {
    int n = tid >> 3, eg = tid & 7;
    float s = bg2g[eg];
#pragma unroll
    for (int k4 = 0; k4 < 32; ++k4) {
      int slot = k4 ^ (n & 7);
      f32x4 hv = *(const f32x4*)(hgs + n * 128 + slot * 4);
      const float* wv = wg2t + eg * 132 + k4 * 4;
      s += hv[0] * wv[0]; s += hv[1] * wv[1]; s += hv[2] * wv[2]; s += hv[3] * wv[3];
    }
    lgg[tid] = s;
  }
  asm volatile("s_waitcnt lgkmcnt(0)" ::: "memory");
  __builtin_amdgcn_s_barrier();

  if (tid < 64) {               // softmax over 8 experts
    float l[8]; float m = -1e30f;
#pragma unroll
    for (int e = 0; e < 8; ++e) { l[e] = lgg[tid * 8 + e]; m = fmaxf(m, l[e]); }
    float s = 0.0f;
#pragma unroll
    for (int e = 0; e < 8; ++e) { l[e] = expf(l[e] - m); s += l[e]; }
    float inv = 1.0f / s;
#pragma unroll
    for (int e = 0; e < 8; ++e) gse[e * 64 + tid] = l[e] * inv;
  }
  asm volatile("s_waitcnt lgkmcnt(0)" ::: "memory");
  __builtin_amdgcn_s_barrier();   // gse visible; hgs (Hs[0]) now dead

  // ---- producer/consumer expert pipeline ----
  // waves 0-3: GEMM1(e=it), own h = pw*64..+63, write Hs[it&1]
  // waves 4-7: GEMM2(e=it-1), own d = pw*64..+63, read Hs[(it-1)&1]
  // acc[4][4]: producer = per-expert hacc (re-zeroed); consumer = oacc
  // accumulated across all experts (disjoint wave paths share the regs).
  int isProd = (wave < 4);
  int pw = wave & 3;

  f32x4 acc[4][4];
#pragma unroll
  for (int i = 0; i < 4; ++i)
#pragma unroll
    for (int j = 0; j < 4; ++j) acc[i][j] = (f32x4){0.f, 0.f, 0.f, 0.f};

#pragma unroll 1
  for (int it = 0; it < 9; ++it) {
    if (isProd) {
      if (it < 8) {
        int e = it;
        const USH* W1e = w1f + (size_t)e * 65536;
#pragma unroll
        for (int i = 0; i < 4; ++i)
#pragma unroll
          for (int j = 0; j < 4; ++j) acc[i][j] = (f32x4){0.f, 0.f, 0.f, 0.f};

        // phase 1: H^T[h,n] = sum_c W1[c,h]*x[n,c]; same (kt,c) order as R14b
#pragma unroll
        for (int kt = 0; kt < 4; ++kt)
#pragma unroll
          for (int c = 0; c < 2; ++c) {
            int cs = ((c * 4 + quad) ^ sw) * 8;
            bf16x8 av[4], bv[4];
#pragma unroll
            for (int i = 0; i < 4; ++i)
              av[i] = *(const bf16x8*)(
                  W1e + (size_t)((kt * 16 + pw * 4 + i) * 2 + c) * 512 + lane * 8);
#pragma unroll
            for (int j = 0; j < 4; ++j)
              bv[j] = *(const bf16x8*)(xs + kt * 4096 + (j * 16 + l16) * 64 + cs);
#pragma unroll
            for (int i = 0; i < 4; ++i)
#pragma unroll
              for (int j = 0; j < 4; ++j)
                acc[i][j] = __builtin_amdgcn_mfma_f32_16x16x32_bf16(
                    av[i], bv[j], acc[i][j], 0, 0, 0);
          }

        // epilogue: Hs[e&1][n][h] = bf16(relu(acc+b1)*g[n,e]), swizzled
        USH* Hb = &Hs[e & 1][0];
#pragma unroll
        for (int i = 0; i < 4; ++i) {
          int slot = i * 2 + (quad >> 1);          // (h>>3)&7 within 64-block
          int hb = pw * 64 + i * 16 + quad * 4;
#pragma unroll
          for (int j = 0; j < 4; ++j) {
            int n = j * 16 + l16;
            float gg = gse[e * 64 + n];
            USH w4[4];
#pragma unroll
            for (int r = 0; r < 4; ++r)
              w4[r] = f2bf(fmaxf(acc[i][j][r] + b1s[e * 256 + hb + r], 0.0f) * gg);
            int off = n * 256 + pw * 64 + ((slot ^ (n & 7)) * 8) + (quad & 1) * 4;
            *(uint2*)(Hb + off) = *(const uint2*)w4;
          }
        }
      }
    } else {
      if (it >= 1) {
        int e = it - 1;
        const USH* W2e = w2f + (size_t)e * 65536;
        const USH* Hb = &Hs[e & 1][0];

        // phase 2: out[n,d] += sum_h Hs[n,h]*W2[h,d]; same (ht,c) order
#pragma unroll
        for (int ht = 0; ht < 4; ++ht)
#pragma unroll
          for (int c = 0; c < 2; ++c) {
            int cs = ((c * 4 + quad) ^ sw) * 8;
            bf16x8 av[4], bv[4];
#pragma unroll
            for (int j = 0; j < 4; ++j)
              bv[j] = *(const bf16x8*)(
                  W2e + (size_t)((ht * 16 + pw * 4 + j) * 2 + c) * 512 + lane * 8);
#pragma unroll
            for (int i = 0; i < 4; ++i)
              av[i] = *(const bf16x8*)(Hb + (i * 16 + l16) * 256 + ht * 64 + cs);
#pragma unroll
            for (int i = 0; i < 4; ++i)
#pragma unroll
              for (int j = 0; j < 4; ++j)
                acc[i][j] = __builtin_amdgcn_mfma_f32_16x16x32_bf16(
                    av[i], bv[j], acc[i][j], 0, 0, 0);
          }
      }
    }
    // per-iteration handoff: Hs writes visible, frag reads done; weight
    // loads (vmcnt) stay in flight across the barrier.
    asm volatile("s_waitcnt lgkmcnt(0)" ::: "memory");
    __builtin_amdgcn_s_barrier();
  }

  // final epilogue (consumer waves): out = acc + sum_e g[n,e]*b2[e,d]
  if (!isProd) {
#pragma unroll
    for (int i = 0; i < 4; ++i)
#pragma unroll
      for (int r = 0; r < 4; ++r) {
        int n = i * 16 + quad * 4 + r;
        size_t grow = (size_t)(rowBase + n) * 256;
#pragma unroll
        for (int j = 0; j < 4; ++j) {
          int d = pw * 64 + j * 16 + l16;
          float bias = 0.0f;
#pragma unroll
          for (int ee = 0; ee < 8; ++ee) bias += gse[ee * 64 + n] * b2s[ee * 256 + d];
          out[grow + d] = acc[i][j][r] + bias;
        }
      }
  }
}

// ---------------- launch ----------------

extern "C" void kernel_launch(void* const* d_in, const int* in_sizes, int n_in,
                              void* d_out, int out_size, void* d_ws, size_t ws_size,
                              hipStream_t stream) {
  const float* x   = (const float*)d_in[0];
  const float* Wg1 = (const float*)d_in[1];
  const float* bg1 = (const float*)d_in[2];
  const float* Wg2 = (const float*)d_in[3];
  const float* bg2 = (const float*)d_in[4];
  const float* W1  = (const float*)d_in[5];
  const float* b1  = (const float*)d_in[6];
  const float* W2  = (const float*)d_in[7];
  const float* b2  = (const float*)d_in[8];
  float* out = (float*)d_out;

  char* ws = (char*)d_ws;
  USH* w1f  = (USH*)(ws + 8388608);
  USH* wg1f = (USH*)(ws + 9437184);
  USH* w2f  = (USH*)(ws + 9502720);

  hipLaunchKernelGGL(k_prep, dim3(264), dim3(256), 0, stream,
                     Wg1, W1, W2, w1f, w2f, wg1f);
  hipLaunchKernelGGL(k_moe, dim3(256), dim3(512), 0, stream,
                     x, w1f, w2f, wg1f, Wg2, bg1, bg2, b1, b2, out);
}